// Round 1
// 839.979 us; speedup vs baseline: 1.1330x; 1.1330x over previous
//
#include <hip/hip_runtime.h>

#define Bdim 2
#define Tdim 2048
#define Edim 4096
#define Hdim 32
#define Ddim 128
#define Mdim (Bdim*Tdim)   // 4096
#define Kdim 4096

typedef int v4i __attribute__((ext_vector_type(4)));

// glds16: HW semantics = wave-uniform base (readfirstlane) + lane*16; we pass
// base + cidx*16 with cidx consecutive in lane order (correct either way).
__device__ __forceinline__ void glds16(const void* g, void* l) {
  __builtin_amdgcn_global_load_lds(
      (const __attribute__((address_space(1))) void*)g,
      (__attribute__((address_space(3))) void*)l, 16, 0, 0);
}

// ---------------- fused pack: 5x int32 -> int8 ----------------
// grid: (SZ/4/256 = 16384, 5); one int4 chunk per thread.
__global__ __launch_bounds__(256) void pack5_kernel(
    const int* __restrict__ s0, const int* __restrict__ s1, const int* __restrict__ s2,
    const int* __restrict__ s3, const int* __restrict__ s4,
    char* __restrict__ d0, char* __restrict__ d1, char* __restrict__ d2,
    char* __restrict__ d3, char* __restrict__ d4) {
  int which = blockIdx.y;
  const int* s = which == 0 ? s0 : which == 1 ? s1 : which == 2 ? s2 : which == 3 ? s3 : s4;
  char* d = which == 0 ? d0 : which == 1 ? d1 : which == 2 ? d2 : which == 3 ? d3 : d4;
  int i = blockIdx.x * 256 + threadIdx.x;
  int4 x = ((const int4*)s)[i];
  char4 y; y.x = (char)x.x; y.y = (char)x.y; y.z = (char)x.z; y.w = (char)x.w;
  ((char4*)d)[i] = y;
}

// ---------------- V transpose: v8[b][s][h*128+d] -> vt[bh][d][s] ----------------
__global__ __launch_bounds__(256) void transpose_v(const char* __restrict__ V8,
                                                   char* __restrict__ Vt) {
  int bh = blockIdx.z, b = bh >> 5, h = bh & 31;
  int s0 = blockIdx.x * 64, d0 = blockIdx.y * 64;
  __shared__ __align__(16) char tl[64 * 80];
  int idx = threadIdx.x;
  {
    int row = idx >> 2, off = (idx & 3) * 16;
    v4i v = *(const v4i*)(V8 + (size_t)(b * Tdim + s0 + row) * Edim + h * Ddim + d0 + off);
    *(v4i*)(tl + row * 80 + off) = v;
  }
  __syncthreads();
  {
    int drow = idx >> 2, soff = (idx & 3) * 16;
    char out[16];
#pragma unroll
    for (int j = 0; j < 16; j++) out[j] = tl[(soff + j) * 80 + drow];
    *(v4i*)(Vt + ((size_t)bh * Ddim + d0 + drow) * Tdim + s0 + soff) = *(v4i*)out;
  }
}

// ---------------- int8 NT GEMM: C[m][n] = sum_k A[m][k]*B[n][k] ----------------
// 256x256 tile, 512 thr (8 waves 2x4), BK=64, 3-buffer LDS pipeline,
// counted vmcnt(4) (T4), raw s_barrier, setprio around MFMA (T5), XCD swizzle (T1).
// Wave (wr,wc) owns a 128x64 sub-tile: acc[8][4] of 16x16 frags.
template<int OUT_MODE>
__global__ __launch_bounds__(512, 2) void gemm_nt_i8(
    const char* __restrict__ A, const char* __restrict__ Bw,
    const int* __restrict__ bias_i, const float* __restrict__ bias_f,
    const float* __restrict__ alpha_p,
    char* __restrict__ out8, float* __restrict__ outf)
{
  const float alpha = alpha_p[0];
  // drain: loop's counted vmcnt waits assume ONLY glds ops are outstanding.
  asm volatile("s_waitcnt vmcnt(0)" ::: "memory");

  const int tid = threadIdx.x;
  const int wave = tid >> 6, lane = tid & 63;
  const int quad = lane >> 4, l16 = lane & 15;
  const int wr = wave >> 2, wc = wave & 3;

  // XCD swizzle: 256 wgs, 8 XCDs, each gets a 4(bm)x8(bn) rect (A 4MB + B 8MB per L2).
  const int wg = blockIdx.x;
  const int xcd = wg & 7, sl = wg >> 3;
  const int bm = (xcd >> 1) * 4 + (sl >> 3);
  const int bn = (xcd & 1) * 8 + (sl & 7);
  const int m0 = bm * 256, n0 = bn * 256;

  __shared__ __align__(16) char sm[3][2][16384];  // 3 bufs x {A,B} x 256row*64B

  // staging: cidx = j*512+tid in [0,1024); LDS linear row*64+q*16 (no swizzle:
  // frag reads spread 8 lanes over each of 8 16B-slot groups -> conflict-free).
  const char* asrc[2]; const char* bsrc[2]; int lo[2];
#pragma unroll
  for (int j = 0; j < 2; j++) {
    int cidx = j * 512 + tid;
    int row = cidx >> 2, q = cidx & 3;
    asrc[j] = A  + (size_t)(m0 + row) * Kdim + q * 16;
    bsrc[j] = Bw + (size_t)(n0 + row) * Kdim + q * 16;
    lo[j] = cidx * 16;
  }

  // frag base offsets: A row = wr*128 + mp*64 + i*16 + l16, k-chunk = quad
  const int aoff = (wr * 128 + l16) * 64 + quad * 16;
  const int boff = (wc * 64  + l16) * 64 + quad * 16;

  v4i acc[8][4];
#pragma unroll
  for (int i = 0; i < 8; i++)
#pragma unroll
    for (int c = 0; c < 4; c++) acc[i][c] = (v4i){0, 0, 0, 0};

  // prologue: stage tiles 0 and 1 (8 glds; issue order defines vmcnt counts)
#pragma unroll
  for (int j = 0; j < 2; j++) glds16(asrc[j],      &sm[0][0][lo[j]]);
#pragma unroll
  for (int j = 0; j < 2; j++) glds16(bsrc[j],      &sm[0][1][lo[j]]);
#pragma unroll
  for (int j = 0; j < 2; j++) glds16(asrc[j] + 64, &sm[1][0][lo[j]]);
#pragma unroll
  for (int j = 0; j < 2; j++) glds16(bsrc[j] + 64, &sm[1][1][lo[j]]);

  int cur = 0, nxt = 2;
  for (int kt = 0; kt < 64; ++kt) {
    const char* As = &sm[cur][0][0];
    const char* Bs = &sm[cur][1][0];
    char* Ad = &sm[nxt][0][0];
    char* Bd = &sm[nxt][1][0];
    const int koff = (kt + 2) * 64;

    // tile kt fully landed iff only tile kt+1's 4 loads remain outstanding.
    if (kt < 63) asm volatile("s_waitcnt vmcnt(4)" ::: "memory");
    else         asm volatile("s_waitcnt vmcnt(0)" ::: "memory");
    __builtin_amdgcn_s_barrier();            // all waves' kt loads landed
    __builtin_amdgcn_sched_barrier(0);       // pin: nothing hoists above barrier

    // ---- phase 0: read frags (mp=0) + B, stage A(kt+2), 16 MFMA ----
    v4i af[4], bf[4];
#pragma unroll
    for (int i = 0; i < 4; i++) af[i] = *(const v4i*)(As + aoff + i * 1024);
#pragma unroll
    for (int c = 0; c < 4; c++) bf[c] = *(const v4i*)(Bs + boff + c * 1024);
    if (kt < 62) {
      glds16(asrc[0] + koff, Ad + lo[0]);
      glds16(asrc[1] + koff, Ad + lo[1]);
    }
    __builtin_amdgcn_s_barrier();
    __builtin_amdgcn_s_setprio(1);
#pragma unroll
    for (int i = 0; i < 4; i++)
#pragma unroll
      for (int c = 0; c < 4; c++)
        acc[i][c] = __builtin_amdgcn_mfma_i32_16x16x64_i8(af[i], bf[c], acc[i][c], 0, 0, 0);
    __builtin_amdgcn_s_setprio(0);

    // ---- phase 1: read frags (mp=1, reuse bf), stage B(kt+2), 16 MFMA ----
#pragma unroll
    for (int i = 0; i < 4; i++) af[i] = *(const v4i*)(As + aoff + 4096 + i * 1024);
    if (kt < 62) {
      glds16(bsrc[0] + koff, Bd + lo[0]);
      glds16(bsrc[1] + koff, Bd + lo[1]);
    }
    __builtin_amdgcn_s_barrier();
    __builtin_amdgcn_s_setprio(1);
#pragma unroll
    for (int i = 0; i < 4; i++)
#pragma unroll
      for (int c = 0; c < 4; c++)
        acc[4 + i][c] = __builtin_amdgcn_mfma_i32_16x16x64_i8(af[i], bf[c], acc[4 + i][c], 0, 0, 0);
    __builtin_amdgcn_s_setprio(0);

    cur = cur == 2 ? 0 : cur + 1;
    nxt = nxt == 2 ? 0 : nxt + 1;
  }

  // epilogue: D frag layout row = quad*4+r, col = l16 (verified convention)
#pragma unroll
  for (int mi = 0; mi < 8; mi++) {
#pragma unroll
    for (int c = 0; c < 4; c++) {
      int gcol = n0 + wc * 64 + c * 16 + l16;
#pragma unroll
      for (int r = 0; r < 4; r++) {
        int grow = m0 + wr * 128 + mi * 16 + quad * 4 + r;
        float y = (float)acc[mi][c][r] * alpha;
        if (OUT_MODE == 0) {
          y += (float)bias_i[gcol];
          int qv = (int)rintf(y);
          qv = qv < -128 ? -128 : (qv > 127 ? 127 : qv);
          out8[(size_t)grow * 4096 + gcol] = (char)qv;
        } else {
          outf[(size_t)grow * 4096 + gcol] = y + bias_f[gcol];
        }
      }
    }
  }
}

// ---------------- fused int8 attention (S^T formulation) ----------------
// grid: (T/64, B*H); block 256 = 4 waves; wave w owns t rows [t0+16w, t0+16w+16)
__global__ __launch_bounds__(256) void attn_kernel(
    const char* __restrict__ Q, const char* __restrict__ Kc, const char* __restrict__ Vt,
    const float* __restrict__ aqk_p, const float* __restrict__ apv_p,
    char* __restrict__ CTX)
{
  const int tid = threadIdx.x;
  const int wave = tid >> 6, lane = tid & 63;
  const int quad = lane >> 4, l16 = lane & 15;
  const int bh = blockIdx.y, b = bh >> 5, h = bh & 31;
  const int t0 = (gridDim.x - 1 - blockIdx.x) * 64;   // heavy blocks first
  const int ntiles = (t0 >> 6) + 1;
  const float a_qk = aqk_p[0], a_pv = apv_p[0];

  __shared__ __align__(16) char qs[64 * 128];   // xor-swizzled rows
  __shared__ __align__(16) char ks[64 * 128];   // xor-swizzled rows
  __shared__ __align__(16) char vts[128 * 64];  // natural [d][s] tile
  __shared__ __align__(16) char ps[4][16 * 80]; // per-wave P^T [t][s], stride 80

  const int t = t0 + 16 * wave + l16;
  const int h7 = l16 & 7;

  // stage Q tile (swizzled)
#pragma unroll
  for (int j = 0; j < 2; j++) {
    int idx = tid + j * 256;
    int row = idx >> 3, ch = idx & 7;
    v4i v = *(const v4i*)(Q + (size_t)(b * Tdim + t0 + row) * Edim + h * Ddim + ch * 16);
    *(v4i*)(qs + row * 128 + ((ch ^ (row & 7)) * 16)) = v;
  }
  __syncthreads();
  v4i qB[2];
#pragma unroll
  for (int kk = 0; kk < 2; kk++)
    qB[kk] = *(const v4i*)(qs + (wave * 16 + l16) * 128 + (((4 * kk + quad) ^ h7) * 16));

  float m_run = -1e30f, l_run = 0.f;

  // ---------- pass 1: exact row max & denom ----------
  for (int it = 0; it < ntiles; ++it) {
    int s0 = it * 64;
    __syncthreads();
#pragma unroll
    for (int j = 0; j < 2; j++) {
      int idx = tid + j * 256;
      int row = idx >> 3, ch = idx & 7;
      v4i v = *(const v4i*)(Kc + (size_t)(b * Tdim + s0 + row) * Edim + h * Ddim + ch * 16);
      *(v4i*)(ks + row * 128 + ((ch ^ (row & 7)) * 16)) = v;
    }
    __syncthreads();

    float sv[4][4];
#pragma unroll
    for (int c = 0; c < 4; c++) {
      v4i acc = (v4i){0, 0, 0, 0};
#pragma unroll
      for (int kk = 0; kk < 2; kk++) {
        v4i aK = *(const v4i*)(ks + (16 * c + l16) * 128 + (((4 * kk + quad) ^ h7) * 16));
        acc = __builtin_amdgcn_mfma_i32_16x16x64_i8(aK, qB[kk], acc, 0, 0, 0);
      }
#pragma unroll
      for (int r = 0; r < 4; r++) {
        int s = s0 + 16 * c + 4 * quad + r;
        sv[c][r] = (s <= t) ? (float)acc[r] * a_qk : -1e30f;
      }
    }
    float mt = -1e30f;
#pragma unroll
    for (int c = 0; c < 4; c++)
#pragma unroll
      for (int r = 0; r < 4; r++) mt = fmaxf(mt, sv[c][r]);
    mt = fmaxf(mt, __shfl_xor(mt, 16));
    mt = fmaxf(mt, __shfl_xor(mt, 32));
    float mn = fmaxf(m_run, mt);
    float ss = 0.f;
#pragma unroll
    for (int c = 0; c < 4; c++)
#pragma unroll
      for (int r = 0; r < 4; r++) ss += __expf(sv[c][r] - mn);
    ss += __shfl_xor(ss, 16);
    ss += __shfl_xor(ss, 32);
    l_run = l_run * __expf(m_run - mn) + ss;
    m_run = mn;
  }

  const float rl = 127.0f / l_run;

  v4i accd[8];
#pragma unroll
  for (int dt = 0; dt < 8; dt++) accd[dt] = (v4i){0, 0, 0, 0};

  // ---------- pass 2: requantize P^T, PV via out^T = V^T . P ----------
  for (int it = 0; it < ntiles; ++it) {
    int s0 = it * 64;
    __syncthreads();
#pragma unroll
    for (int j = 0; j < 2; j++) {
      int idx = tid + j * 256;
      int row = idx >> 3, ch = idx & 7;
      v4i v = *(const v4i*)(Kc + (size_t)(b * Tdim + s0 + row) * Edim + h * Ddim + ch * 16);
      *(v4i*)(ks + row * 128 + ((ch ^ (row & 7)) * 16)) = v;
    }
#pragma unroll
    for (int j = 0; j < 2; j++) {
      int cidx = (wave * 2 + j) * 64 + lane;
      int row = cidx >> 2, off = (cidx & 3) * 16;
      glds16(Vt + ((size_t)bh * Ddim + row) * Tdim + s0 + off, vts + cidx * 16);
    }
    __syncthreads();

#pragma unroll
    for (int c = 0; c < 4; c++) {
      v4i acc = (v4i){0, 0, 0, 0};
#pragma unroll
      for (int kk = 0; kk < 2; kk++) {
        v4i aK = *(const v4i*)(ks + (16 * c + l16) * 128 + (((4 * kk + quad) ^ h7) * 16));
        acc = __builtin_amdgcn_mfma_i32_16x16x64_i8(aK, qB[kk], acc, 0, 0, 0);
      }
      char4 pc;
#pragma unroll
      for (int r = 0; r < 4; r++) {
        int s = s0 + 16 * c + 4 * quad + r;
        float p = 0.f;
        if (s <= t)
          p = rintf(__expf((float)acc[r] * a_qk - m_run) * rl);
        ((char*)&pc)[r] = (char)(int)p;
      }
      *(char4*)(ps[wave] + l16 * 80 + 16 * c + 4 * quad) = pc;
    }
    // per-wave buffer: enforce DS write->read ordering before B-frag read
    asm volatile("s_waitcnt lgkmcnt(0)" ::: "memory");
    v4i bP = *(const v4i*)(ps[wave] + l16 * 80 + quad * 16);
#pragma unroll
    for (int dt = 0; dt < 8; dt++) {
      v4i aV = *(const v4i*)(vts + (16 * dt + l16) * 64 + quad * 16);
      accd[dt] = __builtin_amdgcn_mfma_i32_16x16x64_i8(aV, bP, accd[dt], 0, 0, 0);
    }
  }

  // write ctx int8: lane holds d = 16dt + 4quad + r for its t
  size_t obase = (size_t)(b * Tdim + t) * Edim + h * Ddim;
#pragma unroll
  for (int dt = 0; dt < 8; dt++) {
    char4 oc;
#pragma unroll
    for (int r = 0; r < 4; r++) {
      int q = (int)rintf(a_pv * (float)accd[dt][r]);
      q = q < -128 ? -128 : (q > 127 ? 127 : q);
      ((char*)&oc)[r] = (char)q;
    }
    *(char4*)(CTX + obase + 16 * dt + 4 * quad) = oc;
  }
}

// ---------------- launch ----------------
extern "C" void kernel_launch(void* const* d_in, const int* in_sizes, int n_in,
                              void* d_out, int out_size, void* d_ws, size_t ws_size,
                              hipStream_t stream) {
  const int*   hs  = (const int*)d_in[0];
  const int*   Wq  = (const int*)d_in[1];
  const int*   bq  = (const int*)d_in[2];
  const int*   Wk  = (const int*)d_in[3];
  const int*   bk  = (const int*)d_in[4];
  const int*   Wv  = (const int*)d_in[5];
  const int*   bv  = (const int*)d_in[6];
  const int*   Wo  = (const int*)d_in[7];
  const float* bo  = (const float*)d_in[8];
  // d_in[9] = attention_mask: analytic causal, not read
  const float* aq  = (const float*)d_in[10];
  const float* ak  = (const float*)d_in[11];
  const float* av  = (const float*)d_in[12];
  const float* aqk = (const float*)d_in[13];
  const float* apv = (const float*)d_in[14];
  const float* ao  = (const float*)d_in[15];

  char* ws = (char*)d_ws;
  const size_t SZ = (size_t)Mdim * Edim;   // 16 MiB
  char* h8   = ws + 0 * SZ;
  char* wq8  = ws + 1 * SZ;
  char* wk8  = ws + 2 * SZ;
  char* wv8  = ws + 3 * SZ;
  char* wo8  = ws + 4 * SZ;
  char* q8   = ws + 5 * SZ;
  char* k8   = ws + 6 * SZ;
  char* v8   = ws + 7 * SZ;
  char* vt8  = wq8;                        // reuse after QKV GEMMs
  char* ctx8 = h8;                         // reuse after QKV GEMMs

  pack5_kernel<<<dim3(16384, 5), 256, 0, stream>>>(hs, Wq, Wk, Wv, Wo,
                                                   h8, wq8, wk8, wv8, wo8);

  gemm_nt_i8<0><<<dim3(256), 512, 0, stream>>>(h8, wq8, bq, nullptr, aq, q8, nullptr);
  gemm_nt_i8<0><<<dim3(256), 512, 0, stream>>>(h8, wk8, bk, nullptr, ak, k8, nullptr);
  gemm_nt_i8<0><<<dim3(256), 512, 0, stream>>>(h8, wv8, bv, nullptr, av, v8, nullptr);

  transpose_v<<<dim3(32, 2, 64), 256, 0, stream>>>(v8, vt8);

  attn_kernel<<<dim3(32, 64), 256, 0, stream>>>(q8, k8, vt8, aqk, apv, ctx8);

  gemm_nt_i8<1><<<dim3(256), 512, 0, stream>>>(ctx8, wo8, nullptr, bo, ao, nullptr, (float*)d_out);
}

// Round 2
// 759.621 us; speedup vs baseline: 1.2528x; 1.1058x over previous
//
#include <hip/hip_runtime.h>

#define Bdim 2
#define Tdim 2048
#define Edim 4096
#define Hdim 32
#define Ddim 128
#define Mdim (Bdim*Tdim)   // 4096
#define Kdim 4096

typedef int v4i __attribute__((ext_vector_type(4)));

// glds16: HW semantics = wave-uniform base (readfirstlane) + lane*16; we pass
// base + cidx*16 with cidx consecutive in lane order (correct either way).
__device__ __forceinline__ void glds16(const void* g, void* l) {
  __builtin_amdgcn_global_load_lds(
      (const __attribute__((address_space(1))) void*)g,
      (__attribute__((address_space(3))) void*)l, 16, 0, 0);
}

// ---------------- fused pack: 5x int32 -> int8 ----------------
__global__ __launch_bounds__(256) void pack5_kernel(
    const int* __restrict__ s0, const int* __restrict__ s1, const int* __restrict__ s2,
    const int* __restrict__ s3, const int* __restrict__ s4,
    char* __restrict__ d0, char* __restrict__ d1, char* __restrict__ d2,
    char* __restrict__ d3, char* __restrict__ d4) {
  int which = blockIdx.y;
  const int* s = which == 0 ? s0 : which == 1 ? s1 : which == 2 ? s2 : which == 3 ? s3 : s4;
  char* d = which == 0 ? d0 : which == 1 ? d1 : which == 2 ? d2 : which == 3 ? d3 : d4;
  int i = blockIdx.x * 256 + threadIdx.x;
  int4 x = ((const int4*)s)[i];
  char4 y; y.x = (char)x.x; y.y = (char)x.y; y.z = (char)x.z; y.w = (char)x.w;
  ((char4*)d)[i] = y;
}

// ---------------- V transpose: v8[b][s][h*128+d] -> vt[bh][d][s] ----------------
__global__ __launch_bounds__(256) void transpose_v(const char* __restrict__ V8,
                                                   char* __restrict__ Vt) {
  int bh = blockIdx.z, b = bh >> 5, h = bh & 31;
  int s0 = blockIdx.x * 64, d0 = blockIdx.y * 64;
  __shared__ __align__(16) char tl[64 * 80];
  int idx = threadIdx.x;
  {
    int row = idx >> 2, off = (idx & 3) * 16;
    v4i v = *(const v4i*)(V8 + (size_t)(b * Tdim + s0 + row) * Edim + h * Ddim + d0 + off);
    *(v4i*)(tl + row * 80 + off) = v;
  }
  __syncthreads();
  {
    int drow = idx >> 2, soff = (idx & 3) * 16;
    char out[16];
#pragma unroll
    for (int j = 0; j < 16; j++) out[j] = tl[(soff + j) * 80 + drow];
    *(v4i*)(Vt + ((size_t)bh * Ddim + d0 + drow) * Tdim + s0 + soff) = *(v4i*)out;
  }
}

// ---------------- int8 NT GEMM: C[m][n] = sum_k A[m][k]*B[n][k] ----------------
// 256x256 tile, 512 thr (8 waves 2x4), BK=64, 3-buffer LDS, counted vmcnt(4),
// ONE barrier per K-tile (waves free-run within the epoch -> ds_read/MFMA
// overlap across waves; mid-phase barriers removed R2: they were lockstepping
// the single resident block into LDS-phase/MFMA-phase serialization).
template<int OUT_MODE>
__global__ __launch_bounds__(512, 2) void gemm_nt_i8(
    const char* __restrict__ A, const char* __restrict__ Bw,
    const int* __restrict__ bias_i, const float* __restrict__ bias_f,
    const float* __restrict__ alpha_p,
    char* __restrict__ out8, float* __restrict__ outf)
{
  const float alpha = alpha_p[0];
  // drain: loop's counted vmcnt waits assume ONLY glds ops are outstanding.
  asm volatile("s_waitcnt vmcnt(0)" ::: "memory");

  const int tid = threadIdx.x;
  const int wave = tid >> 6, lane = tid & 63;
  const int quad = lane >> 4, l16 = lane & 15;
  const int wr = wave >> 2, wc = wave & 3;

  // XCD swizzle: 256 wgs, 8 XCDs, each gets a 4(bm)x8(bn) rect.
  const int wg = blockIdx.x;
  const int xcd = wg & 7, sl = wg >> 3;
  const int bm = (xcd >> 1) * 4 + (sl >> 3);
  const int bn = (xcd & 1) * 8 + (sl & 7);
  const int m0 = bm * 256, n0 = bn * 256;

  __shared__ __align__(16) char sm[3][2][16384];  // 3 bufs x {A,B} x 256row*64B

  const char* asrc[2]; const char* bsrc[2]; int lo[2];
#pragma unroll
  for (int j = 0; j < 2; j++) {
    int cidx = j * 512 + tid;
    int row = cidx >> 2, q = cidx & 3;
    asrc[j] = A  + (size_t)(m0 + row) * Kdim + q * 16;
    bsrc[j] = Bw + (size_t)(n0 + row) * Kdim + q * 16;
    lo[j] = cidx * 16;
  }

  // frag base offsets: A row = wr*128 + mp*64 + i*16 + l16, k-chunk = quad
  const int aoff = (wr * 128 + l16) * 64 + quad * 16;
  const int boff = (wc * 64  + l16) * 64 + quad * 16;

  v4i acc[8][4];
#pragma unroll
  for (int i = 0; i < 8; i++)
#pragma unroll
    for (int c = 0; c < 4; c++) acc[i][c] = (v4i){0, 0, 0, 0};

  // prologue: stage tiles 0 and 1 (8 glds; issue order defines vmcnt counts)
#pragma unroll
  for (int j = 0; j < 2; j++) glds16(asrc[j],      &sm[0][0][lo[j]]);
#pragma unroll
  for (int j = 0; j < 2; j++) glds16(bsrc[j],      &sm[0][1][lo[j]]);
#pragma unroll
  for (int j = 0; j < 2; j++) glds16(asrc[j] + 64, &sm[1][0][lo[j]]);
#pragma unroll
  for (int j = 0; j < 2; j++) glds16(bsrc[j] + 64, &sm[1][1][lo[j]]);

  int cur = 0, nxt = 2;
  for (int kt = 0; kt < 64; ++kt) {
    const char* As = &sm[cur][0][0];
    const char* Bs = &sm[cur][1][0];
    char* Ad = &sm[nxt][0][0];
    char* Bd = &sm[nxt][1][0];
    const int koff = (kt + 2) * 64;

    // tile kt fully landed iff only tile kt+1's 4 loads remain outstanding.
    if (kt < 63) asm volatile("s_waitcnt vmcnt(4)" ::: "memory");
    else         asm volatile("s_waitcnt vmcnt(0)" ::: "memory");
    __builtin_amdgcn_s_barrier();            // all waves' kt loads landed
    __builtin_amdgcn_sched_barrier(0);       // pin: no cur-buffer read hoists above

    // frag reads (12 x ds_read_b128) + next-next-tile staging, then one MFMA
    // cluster. No barriers until next epoch: waves drift -> cross-wave overlap.
    v4i af0[4], af1[4], bf[4];
#pragma unroll
    for (int i = 0; i < 4; i++) af0[i] = *(const v4i*)(As + aoff + i * 1024);
#pragma unroll
    for (int c = 0; c < 4; c++) bf[c]  = *(const v4i*)(Bs + boff + c * 1024);
    if (kt < 62) {
      glds16(asrc[0] + koff, Ad + lo[0]);
      glds16(asrc[1] + koff, Ad + lo[1]);
    }
#pragma unroll
    for (int i = 0; i < 4; i++) af1[i] = *(const v4i*)(As + aoff + 4096 + i * 1024);
    if (kt < 62) {
      glds16(bsrc[0] + koff, Bd + lo[0]);
      glds16(bsrc[1] + koff, Bd + lo[1]);
    }

    __builtin_amdgcn_s_setprio(1);
#pragma unroll
    for (int i = 0; i < 4; i++)
#pragma unroll
      for (int c = 0; c < 4; c++)
        acc[i][c] = __builtin_amdgcn_mfma_i32_16x16x64_i8(af0[i], bf[c], acc[i][c], 0, 0, 0);
#pragma unroll
    for (int i = 0; i < 4; i++)
#pragma unroll
      for (int c = 0; c < 4; c++)
        acc[4 + i][c] = __builtin_amdgcn_mfma_i32_16x16x64_i8(af1[i], bf[c], acc[4 + i][c], 0, 0, 0);
    __builtin_amdgcn_s_setprio(0);

    cur = cur == 2 ? 0 : cur + 1;
    nxt = nxt == 2 ? 0 : nxt + 1;
  }

  // epilogue: D frag layout row = quad*4+r, col = l16
#pragma unroll
  for (int mi = 0; mi < 8; mi++) {
#pragma unroll
    for (int c = 0; c < 4; c++) {
      int gcol = n0 + wc * 64 + c * 16 + l16;
#pragma unroll
      for (int r = 0; r < 4; r++) {
        int grow = m0 + wr * 128 + mi * 16 + quad * 4 + r;
        float y = (float)acc[mi][c][r] * alpha;
        if (OUT_MODE == 0) {
          y += (float)bias_i[gcol];
          int qv = (int)rintf(y);
          qv = qv < -128 ? -128 : (qv > 127 ? 127 : qv);
          out8[(size_t)grow * 4096 + gcol] = (char)qv;
        } else {
          outf[(size_t)grow * 4096 + gcol] = y + bias_f[gcol];
        }
      }
    }
  }
}

// ---------------- fused int8 attention (S^T formulation) ----------------
// grid: (32, 64) flattened; XCD-affinity remap: lin%8 picks bh%8 so each XCD
// walks 8 heads bh-major (K/V/Q ~768KB/head stay L2-resident), heavy tiles
// first within each head.
__global__ __launch_bounds__(256) void attn_kernel(
    const char* __restrict__ Q, const char* __restrict__ Kc, const char* __restrict__ Vt,
    const float* __restrict__ aqk_p, const float* __restrict__ apv_p,
    char* __restrict__ CTX)
{
  const int tid = threadIdx.x;
  const int wave = tid >> 6, lane = tid & 63;
  const int quad = lane >> 4, l16 = lane & 15;

  const int lin = blockIdx.y * 32 + blockIdx.x;
  const int xcd = lin & 7, j = lin >> 3;
  const int bh = xcd + 8 * (j >> 5);
  const int b = bh >> 5, h = bh & 31;
  const int t0 = (31 - (j & 31)) * 64;                // heavy blocks first per head
  const int ntiles = (t0 >> 6) + 1;
  const float a_qk = aqk_p[0], a_pv = apv_p[0];

  __shared__ __align__(16) char qs[64 * 128];   // xor-swizzled rows
  __shared__ __align__(16) char ks[64 * 128];   // xor-swizzled rows
  __shared__ __align__(16) char vts[128 * 64];  // natural [d][s] tile
  __shared__ __align__(16) char ps[4][16 * 80]; // per-wave P^T [t][s], stride 80

  const int t = t0 + 16 * wave + l16;
  const int h7 = l16 & 7;

  // stage Q tile (swizzled)
#pragma unroll
  for (int j2 = 0; j2 < 2; j2++) {
    int idx = tid + j2 * 256;
    int row = idx >> 3, ch = idx & 7;
    v4i v = *(const v4i*)(Q + (size_t)(b * Tdim + t0 + row) * Edim + h * Ddim + ch * 16);
    *(v4i*)(qs + row * 128 + ((ch ^ (row & 7)) * 16)) = v;
  }
  __syncthreads();
  v4i qB[2];
#pragma unroll
  for (int kk = 0; kk < 2; kk++)
    qB[kk] = *(const v4i*)(qs + (wave * 16 + l16) * 128 + (((4 * kk + quad) ^ h7) * 16));

  float m_run = -1e30f, l_run = 0.f;

  // ---------- pass 1: exact row max & denom ----------
  for (int it = 0; it < ntiles; ++it) {
    int s0 = it * 64;
    __syncthreads();
#pragma unroll
    for (int j2 = 0; j2 < 2; j2++) {
      int idx = tid + j2 * 256;
      int row = idx >> 3, ch = idx & 7;
      v4i v = *(const v4i*)(Kc + (size_t)(b * Tdim + s0 + row) * Edim + h * Ddim + ch * 16);
      *(v4i*)(ks + row * 128 + ((ch ^ (row & 7)) * 16)) = v;
    }
    __syncthreads();

    float sv[4][4];
#pragma unroll
    for (int c = 0; c < 4; c++) {
      v4i acc = (v4i){0, 0, 0, 0};
#pragma unroll
      for (int kk = 0; kk < 2; kk++) {
        v4i aK = *(const v4i*)(ks + (16 * c + l16) * 128 + (((4 * kk + quad) ^ h7) * 16));
        acc = __builtin_amdgcn_mfma_i32_16x16x64_i8(aK, qB[kk], acc, 0, 0, 0);
      }
#pragma unroll
      for (int r = 0; r < 4; r++) {
        int s = s0 + 16 * c + 4 * quad + r;
        sv[c][r] = (s <= t) ? (float)acc[r] * a_qk : -1e30f;
      }
    }
    float mt = -1e30f;
#pragma unroll
    for (int c = 0; c < 4; c++)
#pragma unroll
      for (int r = 0; r < 4; r++) mt = fmaxf(mt, sv[c][r]);
    mt = fmaxf(mt, __shfl_xor(mt, 16));
    mt = fmaxf(mt, __shfl_xor(mt, 32));
    float mn = fmaxf(m_run, mt);
    float ss = 0.f;
#pragma unroll
    for (int c = 0; c < 4; c++)
#pragma unroll
      for (int r = 0; r < 4; r++) ss += __expf(sv[c][r] - mn);
    ss += __shfl_xor(ss, 16);
    ss += __shfl_xor(ss, 32);
    l_run = l_run * __expf(m_run - mn) + ss;
    m_run = mn;
  }

  const float rl = 127.0f / l_run;

  v4i accd[8];
#pragma unroll
  for (int dt = 0; dt < 8; dt++) accd[dt] = (v4i){0, 0, 0, 0};

  // ---------- pass 2: requantize P^T, PV via out^T = V^T . P ----------
  for (int it = 0; it < ntiles; ++it) {
    int s0 = it * 64;
    __syncthreads();
#pragma unroll
    for (int j2 = 0; j2 < 2; j2++) {
      int idx = tid + j2 * 256;
      int row = idx >> 3, ch = idx & 7;
      v4i v = *(const v4i*)(Kc + (size_t)(b * Tdim + s0 + row) * Edim + h * Ddim + ch * 16);
      *(v4i*)(ks + row * 128 + ((ch ^ (row & 7)) * 16)) = v;
    }
#pragma unroll
    for (int j2 = 0; j2 < 2; j2++) {
      int cidx = (wave * 2 + j2) * 64 + lane;
      int row = cidx >> 2, off = (cidx & 3) * 16;
      glds16(Vt + ((size_t)bh * Ddim + row) * Tdim + s0 + off, vts + cidx * 16);
    }
    __syncthreads();

#pragma unroll
    for (int c = 0; c < 4; c++) {
      v4i acc = (v4i){0, 0, 0, 0};
#pragma unroll
      for (int kk = 0; kk < 2; kk++) {
        v4i aK = *(const v4i*)(ks + (16 * c + l16) * 128 + (((4 * kk + quad) ^ h7) * 16));
        acc = __builtin_amdgcn_mfma_i32_16x16x64_i8(aK, qB[kk], acc, 0, 0, 0);
      }
      char4 pc;
#pragma unroll
      for (int r = 0; r < 4; r++) {
        int s = s0 + 16 * c + 4 * quad + r;
        float p = 0.f;
        if (s <= t)
          p = rintf(__expf((float)acc[r] * a_qk - m_run) * rl);
        ((char*)&pc)[r] = (char)(int)p;
      }
      *(char4*)(ps[wave] + l16 * 80 + 16 * c + 4 * quad) = pc;
    }
    // per-wave buffer: enforce DS write->read ordering before B-frag read
    asm volatile("s_waitcnt lgkmcnt(0)" ::: "memory");
    v4i bP = *(const v4i*)(ps[wave] + l16 * 80 + quad * 16);
#pragma unroll
    for (int dt = 0; dt < 8; dt++) {
      v4i aV = *(const v4i*)(vts + (16 * dt + l16) * 64 + quad * 16);
      accd[dt] = __builtin_amdgcn_mfma_i32_16x16x64_i8(aV, bP, accd[dt], 0, 0, 0);
    }
  }

  // write ctx int8: lane holds d = 16dt + 4quad + r for its t
  size_t obase = (size_t)(b * Tdim + t) * Edim + h * Ddim;
#pragma unroll
  for (int dt = 0; dt < 8; dt++) {
    char4 oc;
#pragma unroll
    for (int r = 0; r < 4; r++) {
      int q = (int)rintf(a_pv * (float)accd[dt][r]);
      q = q < -128 ? -128 : (q > 127 ? 127 : q);
      ((char*)&oc)[r] = (char)q;
    }
    *(char4*)(CTX + obase + 16 * dt + 4 * quad) = oc;
  }
}

// ---------------- launch ----------------
extern "C" void kernel_launch(void* const* d_in, const int* in_sizes, int n_in,
                              void* d_out, int out_size, void* d_ws, size_t ws_size,
                              hipStream_t stream) {
  const int*   hs  = (const int*)d_in[0];
  const int*   Wq  = (const int*)d_in[1];
  const int*   bq  = (const int*)d_in[2];
  const int*   Wk  = (const int*)d_in[3];
  const int*   bk  = (const int*)d_in[4];
  const int*   Wv  = (const int*)d_in[5];
  const int*   bv  = (const int*)d_in[6];
  const int*   Wo  = (const int*)d_in[7];
  const float* bo  = (const float*)d_in[8];
  // d_in[9] = attention_mask: analytic causal, not read
  const float* aq  = (const float*)d_in[10];
  const float* ak  = (const float*)d_in[11];
  const float* av  = (const float*)d_in[12];
  const float* aqk = (const float*)d_in[13];
  const float* apv = (const float*)d_in[14];
  const float* ao  = (const float*)d_in[15];

  char* ws = (char*)d_ws;
  const size_t SZ = (size_t)Mdim * Edim;   // 16 MiB
  char* h8   = ws + 0 * SZ;
  char* wq8  = ws + 1 * SZ;
  char* wk8  = ws + 2 * SZ;
  char* wv8  = ws + 3 * SZ;
  char* wo8  = ws + 4 * SZ;
  char* q8   = ws + 5 * SZ;
  char* k8   = ws + 6 * SZ;
  char* v8   = ws + 7 * SZ;
  char* vt8  = wq8;                        // reuse after QKV GEMMs
  char* ctx8 = h8;                         // reuse after QKV GEMMs

  pack5_kernel<<<dim3(16384, 5), 256, 0, stream>>>(hs, Wq, Wk, Wv, Wo,
                                                   h8, wq8, wk8, wv8, wo8);

  gemm_nt_i8<0><<<dim3(256), 512, 0, stream>>>(h8, wq8, bq, nullptr, aq, q8, nullptr);
  gemm_nt_i8<0><<<dim3(256), 512, 0, stream>>>(h8, wk8, bk, nullptr, ak, k8, nullptr);
  gemm_nt_i8<0><<<dim3(256), 512, 0, stream>>>(h8, wv8, bv, nullptr, av, v8, nullptr);

  transpose_v<<<dim3(32, 2, 64), 256, 0, stream>>>(v8, vt8);

  attn_kernel<<<dim3(32, 64), 256, 0, stream>>>(q8, k8, vt8, aqk, apv, ctx8);

  gemm_nt_i8<1><<<dim3(256), 512, 0, stream>>>(ctx8, wo8, nullptr, bo, ao, nullptr, (float*)d_out);
}